// Round 3
// baseline (176.295 us; speedup 1.0000x reference)
//
#include <hip/hip_runtime.h>
#include <stdint.h>

#define NUM_NODES 50000
#define B_ 4096
#define N_ 100

typedef float f32x4 __attribute__((ext_vector_type(4)));
typedef unsigned int u32x4 __attribute__((ext_vector_type(4)));
typedef short s16x8 __attribute__((ext_vector_type(8)));

__device__ inline unsigned short f2bf(float f) {
    unsigned u = __float_as_uint(f);
    u += 0x7fffu + ((u >> 16) & 1u);
    return (unsigned short)(u >> 16);
}

// ---------------------------------------------------------------------------
// k_pre: blocks 0..1562 -> node_proj = node_raw @ W_feat + b_feat, skill = (int)raw[:,0]
//        last block     -> WgT[dj][dk] = bf16(ln_g[dk]*W_gcn[dk][dj]), hb = ln_b @ W_gcn
// ---------------------------------------------------------------------------
__global__ __launch_bounds__(256) void k_pre(
    const float* __restrict__ node_raw, const float* __restrict__ W_feat,
    const float* __restrict__ b_feat, const float* __restrict__ W_gcn,
    const float* __restrict__ ln_g, const float* __restrict__ ln_b,
    float* __restrict__ proj, int* __restrict__ skill,
    unsigned short* __restrict__ WgT, float* __restrict__ hb)
{
    __shared__ float red[4][64];
    __shared__ float Ws[128 * 64];          // 32 KiB staged W_feat
    int blk = blockIdx.x;
    int t = threadIdx.x;
    int dj = t & 63;

    if (blk == gridDim.x - 1) {             // params block
        int g = t >> 6;                     // dk quarter
        float acc = 0.f;
        #pragma unroll
        for (int i = 0; i < 16; ++i) {
            int dk = g * 16 + i;
            float wv = W_gcn[dk * 64 + dj];
            WgT[dj * 64 + dk] = f2bf(ln_g[dk] * wv);
            acc += ln_b[dk] * wv;
        }
        red[g][dj] = acc;
        __syncthreads();
        if (g == 0) hb[dj] = red[0][dj] + red[1][dj] + red[2][dj] + red[3][dj];
        return;
    }

    // stage W_feat (128x64 f32 = 8192 elems): 32 coalesced rounds
    #pragma unroll
    for (int i = 0; i < 32; ++i) Ws[t + i * 256] = W_feat[t + i * 256];
    __syncthreads();

    int rg = t >> 6;
    int r0 = blk * 32 + rg * 8;
    float acc[8];
    #pragma unroll
    for (int r = 0; r < 8; ++r) acc[r] = 0.f;

    for (int k = 0; k < 128; k += 4) {
        float w0 = Ws[(k + 0) * 64 + dj];
        float w1 = Ws[(k + 1) * 64 + dj];
        float w2 = Ws[(k + 2) * 64 + dj];
        float w3 = Ws[(k + 3) * 64 + dj];
        #pragma unroll
        for (int r = 0; r < 8; ++r) {
            int row = r0 + r;
            int rc = row < NUM_NODES ? row : (NUM_NODES - 1);
            f32x4 rv = *(const f32x4*)(node_raw + (size_t)rc * 128 + k);
            acc[r] += rv.x * w0 + rv.y * w1 + rv.z * w2 + rv.w * w3;
        }
    }
    float bfv = b_feat[dj];
    #pragma unroll
    for (int r = 0; r < 8; ++r) {
        int row = r0 + r;
        if (row < NUM_NODES) proj[(size_t)row * 64 + dj] = acc[r] + bfv;
    }
    if (t < 32) {
        int row = blk * 32 + t;
        if (row < NUM_NODES) skill[row] = (int)node_raw[(size_t)row * 128];
    }
}

// ---------------------------------------------------------------------------
// k_main: one block per sample b. 256 threads = 4 waves.
//   Phase A (2 threads per neighbor row): gather proj row halves into regs,
//            fused = p + u[11]·P[d], in-register LN (one shfl_xor), bf16 pack
//            into chunk-XOR-swizzled LDS xh[112][64].
//   Phase B: h = xhat @ (ln-folded W_gcn) via mfma 16x16x32 bf16
//   Phase C: chain GCN + relu + masked mean-pool (registers + shuffles)
//   Phase D: src/dst @ W_out + b_out
// ---------------------------------------------------------------------------
__global__ __launch_bounds__(256) void k_main(
    const int* __restrict__ ids, const int* __restrict__ eids,
    const float* __restrict__ times, const int* __restrict__ dst_ids,
    const float* __restrict__ edge_raw,
    const float* __restrict__ W_edge, const float* __restrict__ b_edge,
    const float* __restrict__ W_time, const float* __restrict__ b_time,
    const float* __restrict__ W_struct, const float* __restrict__ b_struct,
    const float* __restrict__ w_tenc, const float* __restrict__ b_tenc,
    const float* __restrict__ b_gcn, const float* __restrict__ W_out,
    const float* __restrict__ b_out,
    const float* __restrict__ proj, const int* __restrict__ skill,
    const unsigned short* __restrict__ WgT, const float* __restrict__ hb,
    float* __restrict__ out)
{
    __shared__ float P_s[64][12];             // (wedge, wstr, bias, wtime[0..7], pad)
    __shared__ unsigned short xh[112 * 64];   // bf16, 16B-chunk XOR-swizzled per row
    __shared__ float pooled[64];
    __shared__ int vcnt_w[4];

    int b = blockIdx.x;
    int t = threadIdx.x;
    int lane = t & 63, w = t >> 6;

    // stage params (once)
    if (t < 64) {
        P_s[t][0] = W_edge[t];
        P_s[t][1] = W_struct[t];
        P_s[t][2] = b_edge[t] + b_time[t] + 2.f * b_struct[t];
        #pragma unroll
        for (int i = 0; i < 8; ++i) P_s[t][3 + i] = W_time[i * 64 + t];
        P_s[t][11] = 0.f;
    }

    int dstb = dst_ids[b];
    int n = t >> 1, h = t & 1;

    int id = 0, sk = 0;
    float e = 0.f, tm = 0.f;
    float pr[32];
    if (n < N_) {
        id = ids[b * N_ + n];
        tm = times[b * N_ + n];
        int ei = eids[b * N_ + n];
        e = edge_raw[(size_t)ei * 128];
        sk = skill[id];
        const f32x4* pp = (const f32x4*)(proj + (size_t)id * 64 + h * 32);
        #pragma unroll
        for (int j = 0; j < 8; ++j) *(f32x4*)&pr[j * 4] = pp[j];
    }
    unsigned long long bal = __ballot((h == 0) && (n < N_) && (id > 0));
    if (lane == 0) vcnt_w[w] = __popcll(bal);
    int skdst = skill[dstb];

    float tc[8];
    #pragma unroll
    for (int i = 0; i < 8; ++i) tc[i] = __cosf(fmaf(tm, w_tenc[i], b_tenc[i]));
    float u0 = e;
    float u1 = (id == dstb ? 1.f : 0.f) + (sk == skdst ? 1.f : 0.f);

    __syncthreads();   // P_s ready; vcnt_w ready
    int v = vcnt_w[0] + vcnt_w[1] + vcnt_w[2] + vcnt_w[3];

    // -------- Phase A --------
    if (n < N_) {
        float s1 = 0.f, s2 = 0.f;
        #pragma unroll
        for (int k = 0; k < 32; ++k) {
            int d = h * 32 + k;
            f32x4 P0 = *(const f32x4*)&P_s[d][0];
            f32x4 P1 = *(const f32x4*)&P_s[d][4];
            f32x4 P2 = *(const f32x4*)&P_s[d][8];
            float f = pr[k] + P0.z;
            f = fmaf(u0, P0.x, f);
            f = fmaf(u1, P0.y, f);
            f = fmaf(tc[0], P0.w, f);
            f = fmaf(tc[1], P1.x, f);
            f = fmaf(tc[2], P1.y, f);
            f = fmaf(tc[3], P1.z, f);
            f = fmaf(tc[4], P1.w, f);
            f = fmaf(tc[5], P2.x, f);
            f = fmaf(tc[6], P2.y, f);
            f = fmaf(tc[7], P2.z, f);
            s1 += f;
            s2 = fmaf(f, f, s2);
            pr[k] = f;
        }
        s1 += __shfl_xor(s1, 1, 64);
        s2 += __shfl_xor(s2, 1, 64);
        float mu = s1 * (1.f / 64.f);
        float var = s2 * (1.f / 64.f) - mu * mu;
        float rstd = rsqrtf(var + 1e-5f);
        #pragma unroll
        for (int j = 0; j < 4; ++j) {
            u32x4 rv;
            #pragma unroll
            for (int q = 0; q < 4; ++q) {
                float lo = (pr[j * 8 + q * 2]     - mu) * rstd;
                float hi = (pr[j * 8 + q * 2 + 1] - mu) * rstd;
                rv[q] = (unsigned)f2bf(lo) | ((unsigned)f2bf(hi) << 16);
            }
            int slot = (h * 4 + j) ^ (n & 7);
            *(u32x4*)((char*)xh + n * 128 + slot * 16) = rv;
        }
    } else if (n < 112) {                     // zero pad rows 100..111
        u32x4 z = {0u, 0u, 0u, 0u};
        #pragma unroll
        for (int j = 0; j < 4; ++j)
            *(u32x4*)((char*)xh + n * 128 + (h * 4 + j) * 16) = z;
    }
    __syncthreads();

    // -------- Phase B: MFMA --------
    int col = 16 * w + (lane & 15);
    int kg = lane >> 4;
    s16x8 bfr0 = *(const s16x8*)(WgT + col * 64 + 0 * 32 + kg * 8);
    s16x8 bfr1 = *(const s16x8*)(WgT + col * 64 + 1 * 32 + kg * 8);

    f32x4 acc[7];
    #pragma unroll
    for (int mt = 0; mt < 7; ++mt) { f32x4 z = {0.f,0.f,0.f,0.f}; acc[mt] = z; }
    #pragma unroll
    for (int mt = 0; mt < 7; ++mt) {
        int row = mt * 16 + (lane & 15);
        int ch0 = (0 * 4 + kg) ^ (row & 7);
        int ch1 = (1 * 4 + kg) ^ (row & 7);
        s16x8 a0 = *(const s16x8*)((char*)xh + row * 128 + ch0 * 16);
        acc[mt] = __builtin_amdgcn_mfma_f32_16x16x32_bf16(a0, bfr0, acc[mt], 0, 0, 0);
        s16x8 a1 = *(const s16x8*)((char*)xh + row * 128 + ch1 * 16);
        acc[mt] = __builtin_amdgcn_mfma_f32_16x16x32_bf16(a1, bfr1, acc[mt], 0, 0, 0);
    }

    // -------- Phase C: chain + relu + pool --------
    float hbv = hb[col], bgc = b_gcn[col];
    float carry = 0.f, po = 0.f;
    #pragma unroll
    for (int mt = 0; mt < 7; ++mt) {
        float hh[4];
        hh[0] = acc[mt].x + hbv; hh[1] = acc[mt].y + hbv;
        hh[2] = acc[mt].z + hbv; hh[3] = acc[mt].w + hbv;
        float hup = __shfl_up(hh[3], 16, 64);
        float hpj = (kg > 0) ? hup : carry;
        int nb = mt * 16 + kg * 4;
        #pragma unroll
        for (int j = 0; j < 4; ++j) {
            int nn = nb + j;
            bool hin = (nn >= 1) && (nn < v);
            float a_ = hin ? 0.5f : 1.f;
            float dprev = (nn >= 2 && nn <= v) ? 0.70710678118f : 1.f;
            float coef = hin ? dprev * 0.70710678118f : 0.f;
            float o = hh[j] * a_ + coef * hpj + bgc;
            po += (nn < N_) ? fmaxf(o, 0.f) : 0.f;
            hpj = hh[j];
        }
        carry = __shfl(hh[3], 48 + (lane & 15), 64);
    }
    po += __shfl_xor(po, 16, 64);
    po += __shfl_xor(po, 32, 64);
    if (lane < 16) pooled[col] = po * (1.f / (float)N_);
    __syncthreads();

    // -------- Phase D: output projections --------
    if (w == 0) {
        float o = b_out[lane];
        #pragma unroll 8
        for (int dk = 0; dk < 64; ++dk) o = fmaf(pooled[dk], W_out[dk * 64 + lane], o);
        out[(size_t)b * 64 + lane] = o;
    } else if (w == 1) {
        float o = b_out[lane];
        const float* pd = proj + (size_t)dstb * 64;   // uniform address -> scalar loads
        #pragma unroll 8
        for (int dk = 0; dk < 64; ++dk) o = fmaf(pd[dk], W_out[dk * 64 + lane], o);
        out[(size_t)(B_ + b) * 64 + lane] = o;
    }
}

// ---------------------------------------------------------------------------
extern "C" void kernel_launch(void* const* d_in, const int* in_sizes, int n_in,
                              void* d_out, int out_size, void* d_ws, size_t ws_size,
                              hipStream_t stream)
{
    const int*   ids      = (const int*)d_in[0];
    const int*   eids     = (const int*)d_in[1];
    const float* times    = (const float*)d_in[2];
    const int*   dst_ids  = (const int*)d_in[3];
    const float* node_raw = (const float*)d_in[4];
    const float* edge_raw = (const float*)d_in[5];
    const float* W_feat   = (const float*)d_in[6];
    const float* b_feat   = (const float*)d_in[7];
    const float* W_edge   = (const float*)d_in[8];
    const float* b_edge   = (const float*)d_in[9];
    const float* W_time   = (const float*)d_in[10];
    const float* b_time   = (const float*)d_in[11];
    const float* W_struct = (const float*)d_in[12];
    const float* b_struct = (const float*)d_in[13];
    const float* w_tenc   = (const float*)d_in[14];
    const float* b_tenc   = (const float*)d_in[15];
    const float* ln_g     = (const float*)d_in[16];
    const float* ln_b     = (const float*)d_in[17];
    const float* W_gcn    = (const float*)d_in[18];
    const float* b_gcn    = (const float*)d_in[19];
    const float* W_out    = (const float*)d_in[20];
    const float* b_out    = (const float*)d_in[21];

    char* ws = (char*)d_ws;
    float*          proj   = (float*)ws;                          // 12,800,000 B
    int*            skill  = (int*)(ws + 12800000);               //    200,000 B
    unsigned short* WgT    = (unsigned short*)(ws + 13000000);    //      8,192 B
    float*          hb     = (float*)(ws + 13008192);             //        256 B

    k_pre<<<1564, 256, 0, stream>>>(node_raw, W_feat, b_feat, W_gcn, ln_g, ln_b,
                                    proj, skill, WgT, hb);
    k_main<<<B_, 256, 0, stream>>>(ids, eids, times, dst_ids, edge_raw,
                                   W_edge, b_edge, W_time, b_time, W_struct, b_struct,
                                   w_tenc, b_tenc, b_gcn, W_out, b_out,
                                   proj, skill, WgT, hb, (float*)d_out);
}

// Round 5
// 123.063 us; speedup vs baseline: 1.4326x; 1.4326x over previous
//
#include <hip/hip_runtime.h>
#include <stdint.h>

#define NUM_NODES 50000
#define B_ 4096
#define N_ 100

typedef float f32x4 __attribute__((ext_vector_type(4)));
typedef float f32x2 __attribute__((ext_vector_type(2)));
typedef short s16x8 __attribute__((ext_vector_type(8)));

__device__ inline unsigned short f2bf(float f) {
    unsigned u = __float_as_uint(f);
    u += 0x7fffu + ((u >> 16) & 1u);
    return (unsigned short)(u >> 16);
}

// wave64 sum-reduce on the VALU pipe (DPP), result broadcast to all lanes.
template <int CTRL>
__device__ inline float dpp_add(float x) {
    int t = __builtin_amdgcn_update_dpp(0, __float_as_int(x), CTRL, 0xf, 0xf, true);
    return x + __int_as_float(t);
}
__device__ inline float wave_sum64(float x) {
    x = dpp_add<0x111>(x);   // row_shr:1
    x = dpp_add<0x112>(x);   // row_shr:2
    x = dpp_add<0x114>(x);   // row_shr:4
    x = dpp_add<0x118>(x);   // row_shr:8
    x = dpp_add<0x142>(x);   // row_bcast:15
    x = dpp_add<0x143>(x);   // row_bcast:31
    return __int_as_float(__builtin_amdgcn_readlane(__float_as_int(x), 63));
}

// ---------------------------------------------------------------------------
// k_pre: blocks 0..1562 -> node_proj = node_raw @ W_feat + b_feat, skill = (int)raw[:,0]
//        last block     -> WgT[dj][dk] = bf16(ln_g[dk]*W_gcn[dk][dj]), hb = ln_b @ W_gcn
// ---------------------------------------------------------------------------
__global__ __launch_bounds__(256) void k_pre(
    const float* __restrict__ node_raw, const float* __restrict__ W_feat,
    const float* __restrict__ b_feat, const float* __restrict__ W_gcn,
    const float* __restrict__ ln_g, const float* __restrict__ ln_b,
    float* __restrict__ proj, int* __restrict__ skill,
    unsigned short* __restrict__ WgT, float* __restrict__ hb)
{
    __shared__ float red[4][64];
    __shared__ float Ws[128 * 64];          // 32 KiB staged W_feat
    int blk = blockIdx.x;
    int t = threadIdx.x;
    int dj = t & 63;

    if (blk == gridDim.x - 1) {             // params block
        int g = t >> 6;                     // dk quarter
        float acc = 0.f;
        #pragma unroll
        for (int i = 0; i < 16; ++i) {
            int dk = g * 16 + i;
            float wv = W_gcn[dk * 64 + dj];
            WgT[dj * 64 + dk] = f2bf(ln_g[dk] * wv);
            acc += ln_b[dk] * wv;
        }
        red[g][dj] = acc;
        __syncthreads();
        if (g == 0) hb[dj] = red[0][dj] + red[1][dj] + red[2][dj] + red[3][dj];
        return;
    }

    // stage W_feat (128x64 f32 = 8192 elems): 32 coalesced rounds
    #pragma unroll
    for (int i = 0; i < 32; ++i) Ws[t + i * 256] = W_feat[t + i * 256];
    __syncthreads();

    int rg = t >> 6;
    int r0 = blk * 32 + rg * 8;
    float acc[8];
    #pragma unroll
    for (int r = 0; r < 8; ++r) acc[r] = 0.f;

    for (int k = 0; k < 128; k += 4) {
        float w0 = Ws[(k + 0) * 64 + dj];
        float w1 = Ws[(k + 1) * 64 + dj];
        float w2 = Ws[(k + 2) * 64 + dj];
        float w3 = Ws[(k + 3) * 64 + dj];
        #pragma unroll
        for (int r = 0; r < 8; ++r) {
            int row = r0 + r;
            int rc = row < NUM_NODES ? row : (NUM_NODES - 1);
            f32x4 rv = *(const f32x4*)(node_raw + (size_t)rc * 128 + k);
            acc[r] += rv.x * w0 + rv.y * w1 + rv.z * w2 + rv.w * w3;
        }
    }
    float bfv = b_feat[dj];
    #pragma unroll
    for (int r = 0; r < 8; ++r) {
        int row = r0 + r;
        if (row < NUM_NODES) proj[(size_t)row * 64 + dj] = acc[r] + bfv;
    }
    if (t < 32) {
        int row = blk * 32 + t;
        if (row < NUM_NODES) skill[row] = (int)node_raw[(size_t)row * 128];
    }
}

// ---------------------------------------------------------------------------
// k_main: one block per sample b. 256 threads = 4 waves. (R2 structure,
//   LN reduction moved to DPP/VALU pipe.)
// ---------------------------------------------------------------------------
__global__ __launch_bounds__(256) void k_main(
    const int* __restrict__ ids, const int* __restrict__ eids,
    const float* __restrict__ times, const int* __restrict__ dst_ids,
    const float* __restrict__ edge_raw,
    const float* __restrict__ W_edge, const float* __restrict__ b_edge,
    const float* __restrict__ W_time, const float* __restrict__ b_time,
    const float* __restrict__ W_struct, const float* __restrict__ b_struct,
    const float* __restrict__ w_tenc, const float* __restrict__ b_tenc,
    const float* __restrict__ b_gcn, const float* __restrict__ W_out,
    const float* __restrict__ b_out,
    const float* __restrict__ proj, const int* __restrict__ skill,
    const unsigned short* __restrict__ WgT, const float* __restrict__ hb,
    float* __restrict__ out)
{
    __shared__ int ids_s[N_];
    __shared__ f32x2 ec_s[N_];                // (edge_col, struct_count)
    __shared__ float tenc_s[N_][8];
    __shared__ unsigned short xh[112 * 64];   // bf16, 16B-chunk XOR-swizzled per row
    __shared__ float pooled[64];
    __shared__ float x2[64];
    __shared__ int vcnt_w[4];

    int b = blockIdx.x;
    int t = threadIdx.x;
    int lane = t & 63, w = t >> 6;

    int dstb = dst_ids[b];
    int skdst = skill[dstb];

    // per-lane params (uniform-address -> scalar loads)
    float wedge = W_edge[lane], wstr = W_struct[lane];
    float biasr = b_edge[lane] + b_time[lane] + 2.f * b_struct[lane];
    float wt[8], bt[8], wtime[8];
    #pragma unroll
    for (int i = 0; i < 8; ++i) {
        wt[i] = w_tenc[i]; bt[i] = b_tenc[i]; wtime[i] = W_time[i * 64 + lane];
    }

    // -------- Stage: per-neighbor scalars --------
    int idx_c = t < N_ ? t : N_ - 1;
    int id_t = ids[b * N_ + idx_c];
    float tm_t = times[b * N_ + idx_c];
    int ei_t = eids[b * N_ + idx_c];
    float e_t = edge_raw[(size_t)ei_t * 128];
    int sk_t = skill[id_t];
    unsigned long long bal = __ballot((t < N_) && (id_t > 0));
    if (lane == 0) vcnt_w[w] = __popcll(bal);
    if (t < N_) {
        ids_s[t] = id_t;
        float c = (id_t == dstb ? 1.f : 0.f) + (sk_t == skdst ? 1.f : 0.f);
        f32x2 ec = {e_t, c};
        ec_s[t] = ec;
        #pragma unroll
        for (int i = 0; i < 8; ++i) tenc_s[t][i] = __cosf(fmaf(tm_t, wt[i], bt[i]));
    }
    if (t < 96) {                              // zero pad xh rows 100..111 (1536B)
        f32x4 z = {0.f, 0.f, 0.f, 0.f};
        *(f32x4*)((char*)xh + 100 * 128 + t * 16) = z;
    }
    if (w == 2) x2[lane] = proj[(size_t)dstb * 64 + lane];
    __syncthreads();
    int v = vcnt_w[0] + vcnt_w[1] + vcnt_w[2] + vcnt_w[3];

    // -------- Phase A --------
    int id0 = ids_s[w];
    float p_cur = proj[(size_t)id0 * 64 + lane];
    for (int it = 0; it < 25; ++it) {
        int n = it * 4 + w;
        int nn = (n + 4 < N_) ? n + 4 : N_ - 1;
        int idn = ids_s[nn];
        float p_next = proj[(size_t)idn * 64 + lane];   // prefetch next iter

        f32x2 ec = ec_s[n];
        f32x4 t0 = *(const f32x4*)&tenc_s[n][0];
        f32x4 t1 = *(const f32x4*)&tenc_s[n][4];
        float tf = t0.x * wtime[0];
        tf = fmaf(t0.y, wtime[1], tf);
        tf = fmaf(t0.z, wtime[2], tf);
        tf = fmaf(t0.w, wtime[3], tf);
        tf = fmaf(t1.x, wtime[4], tf);
        tf = fmaf(t1.y, wtime[5], tf);
        tf = fmaf(t1.z, wtime[6], tf);
        tf = fmaf(t1.w, wtime[7], tf);
        float fused = p_cur + fmaf(ec.x, wedge, tf) + fmaf(ec.y, wstr, biasr);

        // LN across the 64-lane wave — DPP on the VALU pipe, no ds traffic
        float s1 = wave_sum64(fused);
        float s2 = wave_sum64(fused * fused);
        float mu = s1 * (1.f / 64.f);
        float var = s2 * (1.f / 64.f) - mu * mu;
        float xhv = (fused - mu) * rsqrtf(var + 1e-5f);
        int chunk = (lane >> 3) ^ (n & 7);
        *(unsigned short*)((char*)xh + n * 128 + chunk * 16 + (lane & 7) * 2) = f2bf(xhv);
        p_cur = p_next;
    }
    __syncthreads();

    // -------- Phase B: MFMA --------
    int col = 16 * w + (lane & 15);
    int kg = lane >> 4;
    s16x8 bfr0 = *(const s16x8*)(WgT + col * 64 + 0 * 32 + kg * 8);
    s16x8 bfr1 = *(const s16x8*)(WgT + col * 64 + 1 * 32 + kg * 8);

    f32x4 acc[7];
    #pragma unroll
    for (int mt = 0; mt < 7; ++mt) { f32x4 z = {0.f,0.f,0.f,0.f}; acc[mt] = z; }
    #pragma unroll
    for (int mt = 0; mt < 7; ++mt) {
        int row = mt * 16 + (lane & 15);
        int ch0 = (0 * 4 + kg) ^ (row & 7);
        int ch1 = (1 * 4 + kg) ^ (row & 7);
        s16x8 a0 = *(const s16x8*)((char*)xh + row * 128 + ch0 * 16);
        acc[mt] = __builtin_amdgcn_mfma_f32_16x16x32_bf16(a0, bfr0, acc[mt], 0, 0, 0);
        s16x8 a1 = *(const s16x8*)((char*)xh + row * 128 + ch1 * 16);
        acc[mt] = __builtin_amdgcn_mfma_f32_16x16x32_bf16(a1, bfr1, acc[mt], 0, 0, 0);
    }

    // -------- Phase C: chain + relu + pool --------
    float hbv = hb[col], bgc = b_gcn[col];
    float carry = 0.f, po = 0.f;
    #pragma unroll
    for (int mt = 0; mt < 7; ++mt) {
        float hh[4];
        hh[0] = acc[mt].x + hbv; hh[1] = acc[mt].y + hbv;
        hh[2] = acc[mt].z + hbv; hh[3] = acc[mt].w + hbv;
        float hup = __shfl_up(hh[3], 16, 64);
        float hpj = (kg > 0) ? hup : carry;
        int nb = mt * 16 + kg * 4;
        #pragma unroll
        for (int j = 0; j < 4; ++j) {
            int nn = nb + j;
            bool hin = (nn >= 1) && (nn < v);
            float a_ = hin ? 0.5f : 1.f;
            float dprev = (nn >= 2 && nn <= v) ? 0.70710678118f : 1.f;
            float coef = hin ? dprev * 0.70710678118f : 0.f;
            float o = hh[j] * a_ + coef * hpj + bgc;
            po += (nn < N_) ? fmaxf(o, 0.f) : 0.f;
            hpj = hh[j];
        }
        carry = __shfl(hh[3], 48 + (lane & 15), 64);
    }
    po += __shfl_xor(po, 16, 64);
    po += __shfl_xor(po, 32, 64);
    if (lane < 16) pooled[col] = po * (1.f / (float)N_);
    __syncthreads();

    // -------- Phase D: output projections --------
    if (w == 0) {
        float o = b_out[lane];
        #pragma unroll 8
        for (int dk = 0; dk < 64; ++dk) o = fmaf(pooled[dk], W_out[dk * 64 + lane], o);
        out[(size_t)b * 64 + lane] = o;
    } else if (w == 1) {
        float o = b_out[lane];
        #pragma unroll 8
        for (int dk = 0; dk < 64; ++dk) o = fmaf(x2[dk], W_out[dk * 64 + lane], o);
        out[(size_t)(B_ + b) * 64 + lane] = o;
    }
}

// ---------------------------------------------------------------------------
extern "C" void kernel_launch(void* const* d_in, const int* in_sizes, int n_in,
                              void* d_out, int out_size, void* d_ws, size_t ws_size,
                              hipStream_t stream)
{
    const int*   ids      = (const int*)d_in[0];
    const int*   eids     = (const int*)d_in[1];
    const float* times    = (const float*)d_in[2];
    const int*   dst_ids  = (const int*)d_in[3];
    const float* node_raw = (const float*)d_in[4];
    const float* edge_raw = (const float*)d_in[5];
    const float* W_feat   = (const float*)d_in[6];
    const float* b_feat   = (const float*)d_in[7];
    const float* W_edge   = (const float*)d_in[8];
    const float* b_edge   = (const float*)d_in[9];
    const float* W_time   = (const float*)d_in[10];
    const float* b_time   = (const float*)d_in[11];
    const float* W_struct = (const float*)d_in[12];
    const float* b_struct = (const float*)d_in[13];
    const float* w_tenc   = (const float*)d_in[14];
    const float* b_tenc   = (const float*)d_in[15];
    const float* ln_g     = (const float*)d_in[16];
    const float* ln_b     = (const float*)d_in[17];
    const float* W_gcn    = (const float*)d_in[18];
    const float* b_gcn    = (const float*)d_in[19];
    const float* W_out    = (const float*)d_in[20];
    const float* b_out    = (const float*)d_in[21];

    char* ws = (char*)d_ws;
    float*          proj   = (float*)ws;                          // 12,800,000 B
    int*            skill  = (int*)(ws + 12800000);               //    200,000 B
    unsigned short* WgT    = (unsigned short*)(ws + 13000000);    //      8,192 B
    float*          hb     = (float*)(ws + 13008192);             //        256 B

    k_pre<<<1564, 256, 0, stream>>>(node_raw, W_feat, b_feat, W_gcn, ln_g, ln_b,
                                    proj, skill, WgT, hb);
    k_main<<<B_, 256, 0, stream>>>(ids, eids, times, dst_ids, edge_raw,
                                   W_edge, b_edge, W_time, b_time, W_struct, b_struct,
                                   w_tenc, b_tenc, b_gcn, W_out, b_out,
                                   proj, skill, WgT, hb, (float*)d_out);
}

// Round 6
// 115.551 us; speedup vs baseline: 1.5257x; 1.0650x over previous
//
#include <hip/hip_runtime.h>
#include <stdint.h>

#define NUM_NODES 50000
#define B_ 4096
#define N_ 100

typedef float f32x4 __attribute__((ext_vector_type(4)));
typedef float f32x2 __attribute__((ext_vector_type(2)));
typedef short s16x8 __attribute__((ext_vector_type(8)));

__device__ inline unsigned short f2bf(float f) {
    unsigned u = __float_as_uint(f);
    u += 0x7fffu + ((u >> 16) & 1u);
    return (unsigned short)(u >> 16);
}

// wave64 sum-reduce on the VALU pipe (DPP), result broadcast to all lanes.
template <int CTRL>
__device__ inline float dpp_add(float x) {
    int t = __builtin_amdgcn_update_dpp(0, __float_as_int(x), CTRL, 0xf, 0xf, true);
    return x + __int_as_float(t);
}
__device__ inline float wave_sum64(float x) {
    x = dpp_add<0x111>(x);   // row_shr:1
    x = dpp_add<0x112>(x);   // row_shr:2
    x = dpp_add<0x114>(x);   // row_shr:4
    x = dpp_add<0x118>(x);   // row_shr:8
    x = dpp_add<0x142>(x);   // row_bcast:15
    x = dpp_add<0x143>(x);   // row_bcast:31
    return __int_as_float(__builtin_amdgcn_readlane(__float_as_int(x), 63));
}

// ---------------------------------------------------------------------------
// k_pre: blocks 0..1562 -> node_proj = node_raw @ W_feat + b_feat, skill = (int)raw[:,0]
//        last block     -> WgT[dj][dk] = bf16(ln_g[dk]*W_gcn[dk][dj]), hb = ln_b @ W_gcn
// ---------------------------------------------------------------------------
__global__ __launch_bounds__(256) void k_pre(
    const float* __restrict__ node_raw, const float* __restrict__ W_feat,
    const float* __restrict__ b_feat, const float* __restrict__ W_gcn,
    const float* __restrict__ ln_g, const float* __restrict__ ln_b,
    float* __restrict__ proj, int* __restrict__ skill,
    unsigned short* __restrict__ WgT, float* __restrict__ hb)
{
    __shared__ float red[4][64];
    __shared__ float Ws[128 * 64];          // 32 KiB staged W_feat
    int blk = blockIdx.x;
    int t = threadIdx.x;
    int dj = t & 63;

    if (blk == gridDim.x - 1) {             // params block
        int g = t >> 6;                     // dk quarter
        float acc = 0.f;
        #pragma unroll
        for (int i = 0; i < 16; ++i) {
            int dk = g * 16 + i;
            float wv = W_gcn[dk * 64 + dj];
            WgT[dj * 64 + dk] = f2bf(ln_g[dk] * wv);
            acc += ln_b[dk] * wv;
        }
        red[g][dj] = acc;
        __syncthreads();
        if (g == 0) hb[dj] = red[0][dj] + red[1][dj] + red[2][dj] + red[3][dj];
        return;
    }

    // stage W_feat (128x64 f32 = 8192 elems): 32 coalesced rounds
    #pragma unroll
    for (int i = 0; i < 32; ++i) Ws[t + i * 256] = W_feat[t + i * 256];
    __syncthreads();

    int rg = t >> 6;
    int r0 = blk * 32 + rg * 8;
    float acc[8];
    #pragma unroll
    for (int r = 0; r < 8; ++r) acc[r] = 0.f;

    for (int k = 0; k < 128; k += 4) {
        float w0 = Ws[(k + 0) * 64 + dj];
        float w1 = Ws[(k + 1) * 64 + dj];
        float w2 = Ws[(k + 2) * 64 + dj];
        float w3 = Ws[(k + 3) * 64 + dj];
        #pragma unroll
        for (int r = 0; r < 8; ++r) {
            int row = r0 + r;
            int rc = row < NUM_NODES ? row : (NUM_NODES - 1);
            f32x4 rv = *(const f32x4*)(node_raw + (size_t)rc * 128 + k);
            acc[r] += rv.x * w0 + rv.y * w1 + rv.z * w2 + rv.w * w3;
        }
    }
    float bfv = b_feat[dj];
    #pragma unroll
    for (int r = 0; r < 8; ++r) {
        int row = r0 + r;
        if (row < NUM_NODES) proj[(size_t)row * 64 + dj] = acc[r] + bfv;
    }
    if (t < 32) {
        int row = blk * 32 + t;
        if (row < NUM_NODES) skill[row] = (int)node_raw[(size_t)row * 128];
    }
}

// ---------------------------------------------------------------------------
// k_main: one block per sample b. 256 threads = 4 waves. (R5 structure,
//   Phase A proj-gather pipelined 5-deep in a statically-indexed register ring.)
// ---------------------------------------------------------------------------
__global__ __launch_bounds__(256) void k_main(
    const int* __restrict__ ids, const int* __restrict__ eids,
    const float* __restrict__ times, const int* __restrict__ dst_ids,
    const float* __restrict__ edge_raw,
    const float* __restrict__ W_edge, const float* __restrict__ b_edge,
    const float* __restrict__ W_time, const float* __restrict__ b_time,
    const float* __restrict__ W_struct, const float* __restrict__ b_struct,
    const float* __restrict__ w_tenc, const float* __restrict__ b_tenc,
    const float* __restrict__ b_gcn, const float* __restrict__ W_out,
    const float* __restrict__ b_out,
    const float* __restrict__ proj, const int* __restrict__ skill,
    const unsigned short* __restrict__ WgT, const float* __restrict__ hb,
    float* __restrict__ out)
{
    __shared__ int ids_s[N_];
    __shared__ f32x2 ec_s[N_];                // (edge_col, struct_count)
    __shared__ float tenc_s[N_][8];
    __shared__ unsigned short xh[112 * 64];   // bf16, 16B-chunk XOR-swizzled per row
    __shared__ float pooled[64];
    __shared__ float x2[64];
    __shared__ int vcnt_w[4];

    int b = blockIdx.x;
    int t = threadIdx.x;
    int lane = t & 63, w = t >> 6;

    int dstb = dst_ids[b];
    int skdst = skill[dstb];

    // per-lane params (uniform-address -> scalar loads)
    float wedge = W_edge[lane], wstr = W_struct[lane];
    float biasr = b_edge[lane] + b_time[lane] + 2.f * b_struct[lane];
    float wt[8], bt[8], wtime[8];
    #pragma unroll
    for (int i = 0; i < 8; ++i) {
        wt[i] = w_tenc[i]; bt[i] = b_tenc[i]; wtime[i] = W_time[i * 64 + lane];
    }

    // -------- Stage: per-neighbor scalars --------
    int idx_c = t < N_ ? t : N_ - 1;
    int id_t = ids[b * N_ + idx_c];
    float tm_t = times[b * N_ + idx_c];
    int ei_t = eids[b * N_ + idx_c];
    float e_t = edge_raw[(size_t)ei_t * 128];
    int sk_t = skill[id_t];
    unsigned long long bal = __ballot((t < N_) && (id_t > 0));
    if (lane == 0) vcnt_w[w] = __popcll(bal);
    if (t < N_) {
        ids_s[t] = id_t;
        float c = (id_t == dstb ? 1.f : 0.f) + (sk_t == skdst ? 1.f : 0.f);
        f32x2 ec = {e_t, c};
        ec_s[t] = ec;
        #pragma unroll
        for (int i = 0; i < 8; ++i) tenc_s[t][i] = __cosf(fmaf(tm_t, wt[i], bt[i]));
    }
    if (t < 96) {                              // zero pad xh rows 100..111 (1536B)
        f32x4 z = {0.f, 0.f, 0.f, 0.f};
        *(f32x4*)((char*)xh + 100 * 128 + t * 16) = z;
    }
    if (w == 2) x2[lane] = proj[(size_t)dstb * 64 + lane];
    __syncthreads();
    int v = vcnt_w[0] + vcnt_w[1] + vcnt_w[2] + vcnt_w[3];

    // -------- Phase A: 5-deep pipelined proj gather --------
    float pc[5], pn[5];
    #pragma unroll
    for (int j = 0; j < 5; ++j)
        pc[j] = proj[(size_t)ids_s[j * 4 + w] * 64 + lane];

    #pragma unroll
    for (int g = 0; g < 5; ++g) {
        if (g < 4) {
            #pragma unroll
            for (int j = 0; j < 5; ++j)
                pn[j] = proj[(size_t)ids_s[(5 * (g + 1) + j) * 4 + w] * 64 + lane];
        }
        #pragma unroll
        for (int j = 0; j < 5; ++j) {
            int n = (5 * g + j) * 4 + w;
            f32x2 ec = ec_s[n];
            f32x4 t0 = *(const f32x4*)&tenc_s[n][0];
            f32x4 t1 = *(const f32x4*)&tenc_s[n][4];
            float tf = t0.x * wtime[0];
            tf = fmaf(t0.y, wtime[1], tf);
            tf = fmaf(t0.z, wtime[2], tf);
            tf = fmaf(t0.w, wtime[3], tf);
            tf = fmaf(t1.x, wtime[4], tf);
            tf = fmaf(t1.y, wtime[5], tf);
            tf = fmaf(t1.z, wtime[6], tf);
            tf = fmaf(t1.w, wtime[7], tf);
            float fused = pc[j] + fmaf(ec.x, wedge, tf) + fmaf(ec.y, wstr, biasr);

            // LN across the 64-lane wave — DPP on the VALU pipe
            float s1 = wave_sum64(fused);
            float s2 = wave_sum64(fused * fused);
            float mu = s1 * (1.f / 64.f);
            float var = s2 * (1.f / 64.f) - mu * mu;
            float xhv = (fused - mu) * rsqrtf(var + 1e-5f);
            int chunk = (lane >> 3) ^ (n & 7);
            *(unsigned short*)((char*)xh + n * 128 + chunk * 16 + (lane & 7) * 2) = f2bf(xhv);
        }
        #pragma unroll
        for (int j = 0; j < 5; ++j) pc[j] = pn[j];
    }
    __syncthreads();

    // -------- Phase B: MFMA --------
    int col = 16 * w + (lane & 15);
    int kg = lane >> 4;
    s16x8 bfr0 = *(const s16x8*)(WgT + col * 64 + 0 * 32 + kg * 8);
    s16x8 bfr1 = *(const s16x8*)(WgT + col * 64 + 1 * 32 + kg * 8);

    f32x4 acc[7];
    #pragma unroll
    for (int mt = 0; mt < 7; ++mt) { f32x4 z = {0.f,0.f,0.f,0.f}; acc[mt] = z; }
    #pragma unroll
    for (int mt = 0; mt < 7; ++mt) {
        int row = mt * 16 + (lane & 15);
        int ch0 = (0 * 4 + kg) ^ (row & 7);
        int ch1 = (1 * 4 + kg) ^ (row & 7);
        s16x8 a0 = *(const s16x8*)((char*)xh + row * 128 + ch0 * 16);
        acc[mt] = __builtin_amdgcn_mfma_f32_16x16x32_bf16(a0, bfr0, acc[mt], 0, 0, 0);
        s16x8 a1 = *(const s16x8*)((char*)xh + row * 128 + ch1 * 16);
        acc[mt] = __builtin_amdgcn_mfma_f32_16x16x32_bf16(a1, bfr1, acc[mt], 0, 0, 0);
    }

    // -------- Phase C: chain + relu + pool --------
    float hbv = hb[col], bgc = b_gcn[col];
    float carry = 0.f, po = 0.f;
    #pragma unroll
    for (int mt = 0; mt < 7; ++mt) {
        float hh[4];
        hh[0] = acc[mt].x + hbv; hh[1] = acc[mt].y + hbv;
        hh[2] = acc[mt].z + hbv; hh[3] = acc[mt].w + hbv;
        float hup = __shfl_up(hh[3], 16, 64);
        float hpj = (kg > 0) ? hup : carry;
        int nb = mt * 16 + kg * 4;
        #pragma unroll
        for (int j = 0; j < 4; ++j) {
            int nn = nb + j;
            bool hin = (nn >= 1) && (nn < v);
            float a_ = hin ? 0.5f : 1.f;
            float dprev = (nn >= 2 && nn <= v) ? 0.70710678118f : 1.f;
            float coef = hin ? dprev * 0.70710678118f : 0.f;
            float o = hh[j] * a_ + coef * hpj + bgc;
            po += (nn < N_) ? fmaxf(o, 0.f) : 0.f;
            hpj = hh[j];
        }
        carry = __shfl(hh[3], 48 + (lane & 15), 64);
    }
    po += __shfl_xor(po, 16, 64);
    po += __shfl_xor(po, 32, 64);
    if (lane < 16) pooled[col] = po * (1.f / (float)N_);
    __syncthreads();

    // -------- Phase D: output projections --------
    if (w == 0) {
        float o = b_out[lane];
        #pragma unroll 8
        for (int dk = 0; dk < 64; ++dk) o = fmaf(pooled[dk], W_out[dk * 64 + lane], o);
        out[(size_t)b * 64 + lane] = o;
    } else if (w == 1) {
        float o = b_out[lane];
        #pragma unroll 8
        for (int dk = 0; dk < 64; ++dk) o = fmaf(x2[dk], W_out[dk * 64 + lane], o);
        out[(size_t)(B_ + b) * 64 + lane] = o;
    }
}

// ---------------------------------------------------------------------------
extern "C" void kernel_launch(void* const* d_in, const int* in_sizes, int n_in,
                              void* d_out, int out_size, void* d_ws, size_t ws_size,
                              hipStream_t stream)
{
    const int*   ids      = (const int*)d_in[0];
    const int*   eids     = (const int*)d_in[1];
    const float* times    = (const float*)d_in[2];
    const int*   dst_ids  = (const int*)d_in[3];
    const float* node_raw = (const float*)d_in[4];
    const float* edge_raw = (const float*)d_in[5];
    const float* W_feat   = (const float*)d_in[6];
    const float* b_feat   = (const float*)d_in[7];
    const float* W_edge   = (const float*)d_in[8];
    const float* b_edge   = (const float*)d_in[9];
    const float* W_time   = (const float*)d_in[10];
    const float* b_time   = (const float*)d_in[11];
    const float* W_struct = (const float*)d_in[12];
    const float* b_struct = (const float*)d_in[13];
    const float* w_tenc   = (const float*)d_in[14];
    const float* b_tenc   = (const float*)d_in[15];
    const float* ln_g     = (const float*)d_in[16];
    const float* ln_b     = (const float*)d_in[17];
    const float* W_gcn    = (const float*)d_in[18];
    const float* b_gcn    = (const float*)d_in[19];
    const float* W_out    = (const float*)d_in[20];
    const float* b_out    = (const float*)d_in[21];

    char* ws = (char*)d_ws;
    float*          proj   = (float*)ws;                          // 12,800,000 B
    int*            skill  = (int*)(ws + 12800000);               //    200,000 B
    unsigned short* WgT    = (unsigned short*)(ws + 13000000);    //      8,192 B
    float*          hb     = (float*)(ws + 13008192);             //        256 B

    k_pre<<<1564, 256, 0, stream>>>(node_raw, W_feat, b_feat, W_gcn, ln_g, ln_b,
                                    proj, skill, WgT, hb);
    k_main<<<B_, 256, 0, stream>>>(ids, eids, times, dst_ids, edge_raw,
                                   W_edge, b_edge, W_time, b_time, W_struct, b_struct,
                                   w_tenc, b_tenc, b_gcn, W_out, b_out,
                                   proj, skill, WgT, hb, (float*)d_out);
}